// Round 10
// baseline (218.344 us; speedup 1.0000x reference)
//
#include <hip/hip_runtime.h>
#include <hip/hip_bf16.h>

#define D_MODEL 1024
#define D_INNER 2048
#define NPROJ   4096   /* 2*D_INNER */
#define D_STATE 16
#define DT_RANK 128
#define XPJ_N   160    /* DT_RANK + 2*D_STATE */
#define SEQLEN  1024
#define BATCH   2
#define NTOK    2048   /* BATCH*SEQLEN */
#define CHUNK   32
#define NCHUNK  (SEQLEN / CHUNK)   /* 32 */
#define SPLITK  8      /* gemm4 split */
#define OP_SPLITK 4    /* out_proj split */

typedef short short8 __attribute__((ext_vector_type(8)));
typedef unsigned short ushort8v __attribute__((ext_vector_type(8)));
typedef unsigned short ushort4v __attribute__((ext_vector_type(4)));
typedef float f32x4 __attribute__((ext_vector_type(4)));

__device__ __forceinline__ float sigmoidf_(float x) { return 1.f / (1.f + __expf(-x)); }
__device__ __forceinline__ ushort f2bf_bits(float f) {
    __hip_bfloat16 h = __float2bfloat16(f);
    return *(ushort*)&h;
}
__device__ __forceinline__ float bf2f(ushort u) {
    union { unsigned int i; float f; } v;
    v.i = ((unsigned int)u) << 16;
    return v.f;
}
#define LOG2E 1.44269504088896f

// ---------------- LayerNorm → bf16 output ----------------
__global__ __launch_bounds__(256) void ln_kernel(const float* __restrict__ x,
                                                 const float* __restrict__ g,
                                                 const float* __restrict__ be,
                                                 ushort* __restrict__ hb)
{
    int row = blockIdx.x;
    const float4* xr = (const float4*)(x + (long)row * D_MODEL);
    float4 v = xr[threadIdx.x];
    float s1 = v.x + v.y + v.z + v.w;
    float s2 = v.x*v.x + v.y*v.y + v.z*v.z + v.w*v.w;
    for (int off = 32; off >= 1; off >>= 1) {
        s1 += __shfl_down(s1, off);
        s2 += __shfl_down(s2, off);
    }
    __shared__ float red[8];
    int wid = threadIdx.x >> 6;
    if ((threadIdx.x & 63) == 0) { red[wid] = s1; red[4 + wid] = s2; }
    __syncthreads();
    float mu  = (red[0] + red[1] + red[2] + red[3]) * (1.f / D_MODEL);
    float ex2 = (red[4] + red[5] + red[6] + red[7]) * (1.f / D_MODEL);
    float inv = rsqrtf(ex2 - mu * mu + 1e-5f);
    float4 g4 = ((const float4*)g)[threadIdx.x];
    float4 b4 = ((const float4*)be)[threadIdx.x];
    ushort4 o;
    o.x = f2bf_bits((v.x - mu) * inv * g4.x + b4.x);
    o.y = f2bf_bits((v.y - mu) * inv * g4.y + b4.y);
    o.z = f2bf_bits((v.z - mu) * inv * g4.z + b4.z);
    o.w = f2bf_bits((v.w - mu) * inv * g4.w + b4.w);
    *(ushort4*)(hb + (long)row * D_MODEL + threadIdx.x * 4) = o;
}

// ---------------- f32 [R][C] → bf16 [C][R] transpose (guarded) ----------------
__global__ __launch_bounds__(256) void transpose_bf16_kernel(const float* __restrict__ in,
                                                             ushort* __restrict__ out,
                                                             int R, int C)
{
    __shared__ float tile[64][65];
    int c0 = blockIdx.x * 64, r0 = blockIdx.y * 64;
    #pragma unroll
    for (int i = 0; i < 16; ++i) {
        int idx = threadIdx.x + i * 256;
        int r = idx >> 6, c = idx & 63;
        tile[r][c] = (r0 + r < R && c0 + c < C) ? in[(long)(r0 + r) * C + (c0 + c)] : 0.f;
    }
    __syncthreads();
    #pragma unroll
    for (int i = 0; i < 16; ++i) {
        int idx = threadIdx.x + i * 256;
        int cc = idx >> 6, rr = idx & 63;
        if (c0 + cc < C && r0 + rr < R)
            out[(long)(c0 + cc) * R + (r0 + rr)] = f2bf_bits(tile[rr][cc]);
    }
}

// ---------------- bf16 [R][C] → bf16 [C][R] transpose (R,C multiples of 64) ----------
__global__ __launch_bounds__(256) void transpose_bb_kernel(const ushort* __restrict__ in,
                                                           ushort* __restrict__ out,
                                                           int R, int C)
{
    __shared__ ushort tile[64][68];
    int c0 = blockIdx.x * 64, r0 = blockIdx.y * 64;
    #pragma unroll
    for (int i = 0; i < 4; ++i) {
        int idx = threadIdx.x + i * 256;           // 1024 = 64 rows x 16 u4
        int r = idx >> 4, cq = idx & 15;
        ushort4v v = *(const ushort4v*)(in + (long)(r0 + r) * C + c0 + cq * 4);
        *(ushort4v*)&tile[r][cq * 4] = v;
    }
    __syncthreads();
    #pragma unroll
    for (int i = 0; i < 4; ++i) {
        int idx = threadIdx.x + i * 256;
        int cc = idx >> 4, rq = idx & 15;
        ushort4v v;
        v.x = tile[rq * 4 + 0][cc];
        v.y = tile[rq * 4 + 1][cc];
        v.z = tile[rq * 4 + 2][cc];
        v.w = tile[rq * 4 + 3][cc];
        *(ushort4v*)(out + (long)(c0 + cc) * R + r0 + rq * 4) = v;
    }
}

// ---------------- bf16 MFMA GEMM 128x128: C = A[M,K(lda)] * Bt[N,K(ldb)]^T -----------
// blockIdx.z advances A,Bt by z*K and Cf by z*M*N (split-K).
// EPI 0: v=acc ; EPI 1: v=softplus(acc+bias[n])
// OMODE 0: f32 to Cf[row*N+col]
// OMODE 2: xz-split: col<D_INNER → bf16 Cb[row*D_INNER+col];
//          col>=D_INNER → bf16 Cb2[(col-D_INNER)*M + row] packed ushort4
template <int EPI, int OMODE>
__global__ __launch_bounds__(256) void gemm_mfma_kernel(const ushort* __restrict__ A,
                                                        const ushort* __restrict__ Bt,
                                                        const float* __restrict__ bias,
                                                        float* __restrict__ Cf,
                                                        ushort* __restrict__ Cb,
                                                        ushort* __restrict__ Cb2,
                                                        int M, int N, int K, int lda, int ldb)
{
    long zoff = (long)blockIdx.z;
    A  += zoff * K;
    Bt += zoff * K;
    if (OMODE == 0) Cf += zoff * (long)M * N;
    __shared__ __align__(16) ushort Al[128 * 32];
    __shared__ __align__(16) ushort Bl[128 * 32];
    int tid = threadIdx.x;
    int lane = tid & 63;
    int w = tid >> 6, wr = w >> 1, wc = w & 1;
    int m0 = blockIdx.y * 128, n0 = blockIdx.x * 128;
    f32x4 acc[4][4];
    #pragma unroll
    for (int m = 0; m < 4; ++m)
        #pragma unroll
        for (int n = 0; n < 4; ++n) acc[m][n] = (f32x4){0.f, 0.f, 0.f, 0.f};
    int l15 = lane & 15, kq = lane >> 4;

    for (int k0 = 0; k0 < K; k0 += 32) {
        #pragma unroll
        for (int i = 0; i < 2; ++i) {
            int s = i * 256 + tid;
            int row = s >> 2, kg = s & 3;
            int kgl = kg ^ ((row >> 1) & 3);
            __builtin_amdgcn_global_load_lds(
                (const __attribute__((address_space(1))) void*)(A + (long)(m0 + row) * lda + k0 + kgl * 8),
                (__attribute__((address_space(3))) void*)(Al + s * 8), 16, 0, 0);
            __builtin_amdgcn_global_load_lds(
                (const __attribute__((address_space(1))) void*)(Bt + (long)(n0 + row) * ldb + k0 + kgl * 8),
                (__attribute__((address_space(3))) void*)(Bl + s * 8), 16, 0, 0);
        }
        __syncthreads();
        short8 af[4], bf[4];
        #pragma unroll
        for (int m = 0; m < 4; ++m) {
            int row = wr * 64 + m * 16 + l15;
            af[m] = *(const short8*)&Al[row * 32 + (kq ^ ((row >> 1) & 3)) * 8];
        }
        #pragma unroll
        for (int n = 0; n < 4; ++n) {
            int row = wc * 64 + n * 16 + l15;
            bf[n] = *(const short8*)&Bl[row * 32 + (kq ^ ((row >> 1) & 3)) * 8];
        }
        #pragma unroll
        for (int m = 0; m < 4; ++m)
            #pragma unroll
            for (int n = 0; n < 4; ++n)
                acc[m][n] = __builtin_amdgcn_mfma_f32_16x16x32_bf16(af[m], bf[n], acc[m][n], 0, 0, 0);
        __syncthreads();
    }
    #pragma unroll
    for (int m = 0; m < 4; ++m) {
        #pragma unroll
        for (int n = 0; n < 4; ++n) {
            int rowb = m0 + wr * 64 + m * 16 + kq * 4;
            int col  = n0 + wc * 64 + n * 16 + l15;
            float v0[4];
            #pragma unroll
            for (int r = 0; r < 4; ++r) {
                float v = acc[m][n][r];
                if (EPI == 1) {
                    v += bias[col];
                    v = (v > 20.f) ? v : log1pf(__expf(v));
                }
                v0[r] = v;
            }
            if (OMODE == 0) {
                #pragma unroll
                for (int r = 0; r < 4; ++r)
                    Cf[(long)(rowb + r) * N + col] = v0[r];
            } else { // OMODE 2
                if (col < D_INNER) {
                    #pragma unroll
                    for (int r = 0; r < 4; ++r)
                        Cb[(long)(rowb + r) * D_INNER + col] = f2bf_bits(v0[r]);
                } else {
                    ushort4v pk;
                    pk.x = f2bf_bits(v0[0]); pk.y = f2bf_bits(v0[1]);
                    pk.z = f2bf_bits(v0[2]); pk.w = f2bf_bits(v0[3]);
                    *(ushort4v*)(Cb2 + (long)(col - D_INNER) * M + rowb) = pk;
                }
            }
        }
    }
}

// ---------------- bf16 MFMA GEMM 128x64, transposed bf16 store (for delta^T) ---------
// EPI 1: v=softplus(acc+bias[n]); store CbT[col*M + row] packed ushort4.
__global__ __launch_bounds__(256) void gemm_mfma64T_kernel(const ushort* __restrict__ A,
                                                           const ushort* __restrict__ Bt,
                                                           const float* __restrict__ bias,
                                                           ushort* __restrict__ CbT,
                                                           int M, int N, int K)
{
    __shared__ __align__(16) ushort Al[128 * 32];
    __shared__ __align__(16) ushort Bl[64 * 32];
    int tid = threadIdx.x;
    int lane = tid & 63;
    int w = tid >> 6, wr = w >> 1, wc = w & 1;
    int m0 = blockIdx.y * 128, n0 = blockIdx.x * 64;
    f32x4 acc[4][2];
    #pragma unroll
    for (int m = 0; m < 4; ++m)
        #pragma unroll
        for (int n = 0; n < 2; ++n) acc[m][n] = (f32x4){0.f, 0.f, 0.f, 0.f};
    int l15 = lane & 15, kq = lane >> 4;

    for (int k0 = 0; k0 < K; k0 += 32) {
        #pragma unroll
        for (int i = 0; i < 2; ++i) {
            int s = i * 256 + tid;
            int row = s >> 2, kg = s & 3;
            int kgl = kg ^ ((row >> 1) & 3);
            __builtin_amdgcn_global_load_lds(
                (const __attribute__((address_space(1))) void*)(A + (long)(m0 + row) * K + k0 + kgl * 8),
                (__attribute__((address_space(3))) void*)(Al + s * 8), 16, 0, 0);
        }
        {
            int s = tid;
            int row = s >> 2, kg = s & 3;
            int kgl = kg ^ ((row >> 1) & 3);
            __builtin_amdgcn_global_load_lds(
                (const __attribute__((address_space(1))) void*)(Bt + (long)(n0 + row) * K + k0 + kgl * 8),
                (__attribute__((address_space(3))) void*)(Bl + s * 8), 16, 0, 0);
        }
        __syncthreads();
        short8 af[4], bf[2];
        #pragma unroll
        for (int m = 0; m < 4; ++m) {
            int row = wr * 64 + m * 16 + l15;
            af[m] = *(const short8*)&Al[row * 32 + (kq ^ ((row >> 1) & 3)) * 8];
        }
        #pragma unroll
        for (int n = 0; n < 2; ++n) {
            int row = wc * 32 + n * 16 + l15;
            bf[n] = *(const short8*)&Bl[row * 32 + (kq ^ ((row >> 1) & 3)) * 8];
        }
        #pragma unroll
        for (int m = 0; m < 4; ++m)
            #pragma unroll
            for (int n = 0; n < 2; ++n)
                acc[m][n] = __builtin_amdgcn_mfma_f32_16x16x32_bf16(af[m], bf[n], acc[m][n], 0, 0, 0);
        __syncthreads();
    }
    #pragma unroll
    for (int m = 0; m < 4; ++m) {
        #pragma unroll
        for (int n = 0; n < 2; ++n) {
            int rowb = m0 + wr * 64 + m * 16 + kq * 4;
            int col  = n0 + wc * 32 + n * 16 + l15;
            ushort4v pk;
            #pragma unroll
            for (int r = 0; r < 4; ++r) {
                float v = acc[m][n][r] + bias[col];
                v = (v > 20.f) ? v : log1pf(__expf(v));
                ((ushort*)&pk)[r] = f2bf_bits(v);
            }
            *(ushort4v*)(CbT + (long)col * M + rowb) = pk;
        }
    }
}

// -------- out_proj split-K reduce: out = sum_k Ppart[k] + resid --------
__global__ __launch_bounds__(256) void reduce_out_kernel(const float* __restrict__ Ppart,
                                                         const float* __restrict__ resid,
                                                         float* __restrict__ out)
{
    long i = (long)blockIdx.x * 256 + threadIdx.x;
    const long STRIDE = (long)NTOK * D_MODEL / 4;
    float4 s = ((const float4*)Ppart)[i];
    #pragma unroll
    for (int k = 1; k < OP_SPLITK; ++k) {
        float4 p = ((const float4*)Ppart)[k * STRIDE + i];
        s.x += p.x; s.y += p.y; s.z += p.z; s.w += p.w;
    }
    float4 r = ((const float4*)resid)[i];
    s.x += r.x; s.y += r.y; s.z += r.z; s.w += r.w;
    ((float4*)out)[i] = s;
}

// -------- split-K bf16 MFMA GEMM for xpj --------
__global__ __launch_bounds__(256) void gemm4_mfma_kernel(const ushort* __restrict__ A,
                                                         const ushort* __restrict__ Bt,
                                                         float* __restrict__ Ppart,
                                                         int M, int K)
{
    __shared__ __align__(16) ushort Al[64 * 32];
    __shared__ __align__(16) ushort Bl[160 * 32];
    int tid = threadIdx.x;
    int lane = tid & 63;
    int w = tid >> 6, wr = w >> 1, wc = w & 1;
    int sk = blockIdx.x;
    int m0 = blockIdx.y * 64;
    int kbase = sk * (K / SPLITK);
    f32x4 acc[2][5];
    #pragma unroll
    for (int m = 0; m < 2; ++m)
        #pragma unroll
        for (int n = 0; n < 5; ++n) acc[m][n] = (f32x4){0.f, 0.f, 0.f, 0.f};
    int l15 = lane & 15, kq = lane >> 4;

    for (int ks = 0; ks < K / SPLITK; ks += 32) {
        int k0 = kbase + ks;
        {
            int s = tid;
            int row = s >> 2, kg = s & 3;
            int kgl = kg ^ ((row >> 1) & 3);
            __builtin_amdgcn_global_load_lds(
                (const __attribute__((address_space(1))) void*)(A + (long)(m0 + row) * K + k0 + kgl * 8),
                (__attribute__((address_space(3))) void*)(Al + s * 8), 16, 0, 0);
        }
        #pragma unroll
        for (int i = 0; i < 3; ++i) {
            int s = i * 256 + tid;
            if (s < 640) {
                int row = s >> 2, kg = s & 3;
                int kgl = kg ^ ((row >> 1) & 3);
                __builtin_amdgcn_global_load_lds(
                    (const __attribute__((address_space(1))) void*)(Bt + (long)row * K + k0 + kgl * 8),
                    (__attribute__((address_space(3))) void*)(Bl + s * 8), 16, 0, 0);
            }
        }
        __syncthreads();
        short8 af[2], bf[5];
        #pragma unroll
        for (int m = 0; m < 2; ++m) {
            int row = wr * 32 + m * 16 + l15;
            af[m] = *(const short8*)&Al[row * 32 + (kq ^ ((row >> 1) & 3)) * 8];
        }
        #pragma unroll
        for (int n = 0; n < 5; ++n) {
            int row = wc * 80 + n * 16 + l15;
            bf[n] = *(const short8*)&Bl[row * 32 + (kq ^ ((row >> 1) & 3)) * 8];
        }
        #pragma unroll
        for (int m = 0; m < 2; ++m)
            #pragma unroll
            for (int n = 0; n < 5; ++n)
                acc[m][n] = __builtin_amdgcn_mfma_f32_16x16x32_bf16(af[m], bf[n], acc[m][n], 0, 0, 0);
        __syncthreads();
    }
    float* P = Ppart + (long)sk * M * XPJ_N;
    #pragma unroll
    for (int m = 0; m < 2; ++m) {
        #pragma unroll
        for (int n = 0; n < 5; ++n) {
            #pragma unroll
            for (int r = 0; r < 4; ++r) {
                int row = m0 + wr * 32 + m * 16 + kq * 4 + r;
                int col = wc * 80 + n * 16 + l15;
                P[(long)row * XPJ_N + col] = acc[m][n][r];
            }
        }
    }
}

// -------- reduce split-K partials → xpj f32 + dt_r bf16 --------
__global__ __launch_bounds__(256) void reduce_xpj_kernel(const float* __restrict__ Ppart,
                                                         float* __restrict__ xpj,
                                                         ushort* __restrict__ dtr)
{
    long i = (long)blockIdx.x * 256 + threadIdx.x;
    float s = 0.f;
    #pragma unroll
    for (int k = 0; k < SPLITK; ++k) s += Ppart[k * (long)NTOK * XPJ_N + i];
    xpj[i] = s;
    int col = (int)(i % XPJ_N);
    long row = i / XPJ_N;
    if (col < DT_RANK) dtr[row * DT_RANK + col] = f2bf_bits(s);
}

// ---------------- depthwise causal conv (width 4) + bias + SiLU; bf16 in/out ----------
// xzb: [NTOK][D_INNER]
__global__ __launch_bounds__(256) void conv_silu_kernel(const ushort* __restrict__ xzb,
                                                        const float* __restrict__ cw,
                                                        const float* __restrict__ cb,
                                                        ushort* __restrict__ xbb)
{
    long i = (long)blockIdx.x * 256 + threadIdx.x;  // over NTOK*D_INNER
    int d = (int)(i & (D_INNER - 1));
    long tok = i >> 11;
    int l = (int)(tok & (SEQLEN - 1));
    float w0 = cw[d * 4 + 0], w1 = cw[d * 4 + 1], w2 = cw[d * 4 + 2], w3 = cw[d * 4 + 3];
    float acc = cb[d];
    acc += bf2f(xzb[tok * D_INNER + d]) * w3;
    if (l >= 1) acc += bf2f(xzb[(tok - 1) * D_INNER + d]) * w2;
    if (l >= 2) acc += bf2f(xzb[(tok - 2) * D_INNER + d]) * w1;
    if (l >= 3) acc += bf2f(xzb[(tok - 3) * D_INNER + d]) * w0;
    float v = acc * sigmoidf_(acc);
    xbb[i] = f2bf_bits(v);
}

// ======================= chunked selective scan, time-contiguous layouts ==============
// deltaT, xbT, zT, yT: [D_INNER? no — D_INNER rows][NTOK] bf16. 4 lanes/channel, CHUNK=32.
__global__ __launch_bounds__(256) void scan_partial_kernel(const ushort* __restrict__ deltaT,
                                                           const ushort* __restrict__ xbT,
                                                           const float* __restrict__ xpj,
                                                           const float* __restrict__ A_log,
                                                           float* __restrict__ Pout,
                                                           float* __restrict__ Hout)
{
    int tid = threadIdx.x;
    int j = tid & 3, grp = tid >> 2;
    long gidx = (long)blockIdx.x * 64 + grp;      // over BATCH*NCHUNK*D_INNER
    int d = (int)(gidx & (D_INNER - 1));
    int c = (int)((gidx >> 11) & (NCHUNK - 1));
    int b = (int)(gidx >> 16);
    float4 al = *(const float4*)&A_log[d * D_STATE + 4 * j];
    float a0 = -__expf(al.x) * LOG2E, a1 = -__expf(al.y) * LOG2E;
    float a2 = -__expf(al.z) * LOG2E, a3 = -__expf(al.w) * LOG2E;
    float h0 = 0.f, h1 = 0.f, h2 = 0.f, h3 = 0.f, cum = 0.f;
    long tok0 = (long)b * SEQLEN + c * CHUNK;
    const ushort* dp = deltaT + (long)d * NTOK + tok0;
    const ushort* xp = xbT + (long)d * NTOK + tok0;
    const float* Bp = xpj + tok0 * XPJ_N + DT_RANK + 4 * j;
    #pragma unroll
    for (int t8 = 0; t8 < CHUNK / 8; ++t8) {
        ushort8v dl8 = *(const ushort8v*)dp; dp += 8;
        ushort8v x8  = *(const ushort8v*)xp; xp += 8;
        #pragma unroll
        for (int k = 0; k < 8; ++k) {
            float dl = bf2f(dl8[k]);
            float x  = bf2f(x8[k]);
            float4 Bv = *(const float4*)Bp; Bp += XPJ_N;
            cum += dl;
            float ux = dl * x;
            h0 = exp2f(dl * a0) * h0 + ux * Bv.x;
            h1 = exp2f(dl * a1) * h1 + ux * Bv.y;
            h2 = exp2f(dl * a2) * h2 + ux * Bv.z;
            h3 = exp2f(dl * a3) * h3 + ux * Bv.w;
        }
    }
    long o = gidx * D_STATE + 4 * j;
    *(float4*)&Pout[o] = (float4){exp2f(a0 * cum), exp2f(a1 * cum), exp2f(a2 * cum), exp2f(a3 * cum)};
    *(float4*)&Hout[o] = (float4){h0, h1, h2, h3};
}

__global__ __launch_bounds__(256) void scan_chunkscan_kernel(const float* __restrict__ P,
                                                             const float* __restrict__ H,
                                                             float* __restrict__ hinit)
{
    long i = (long)blockIdx.x * 256 + threadIdx.x;  // over BATCH*D_INNER*D_STATE
    int n = (int)(i & (D_STATE - 1));
    int d = (int)((i >> 4) & (D_INNER - 1));
    int b = (int)(i >> 15);
    float h = 0.f;
    for (int c = 0; c < NCHUNK; ++c) {
        long o = ((((long)b * NCHUNK + c) * D_INNER + d) * D_STATE) + n;
        hinit[o] = h;
        h = P[o] * h + H[o];
    }
}

__global__ __launch_bounds__(256) void scan_final_kernel(const ushort* __restrict__ deltaT,
                                                         const ushort* __restrict__ xbT,
                                                         const float* __restrict__ xpj,
                                                         const ushort* __restrict__ zT,
                                                         const float* __restrict__ A_log,
                                                         const float* __restrict__ Dp,
                                                         const float* __restrict__ hinit,
                                                         ushort* __restrict__ yT)
{
    int tid = threadIdx.x;
    int j = tid & 3, grp = tid >> 2;
    long gidx = (long)blockIdx.x * 64 + grp;
    int d = (int)(gidx & (D_INNER - 1));
    int c = (int)((gidx >> 11) & (NCHUNK - 1));
    int b = (int)(gidx >> 16);
    float4 al = *(const float4*)&A_log[d * D_STATE + 4 * j];
    float a0 = -__expf(al.x) * LOG2E, a1 = -__expf(al.y) * LOG2E;
    float a2 = -__expf(al.z) * LOG2E, a3 = -__expf(al.w) * LOG2E;
    float dpar = Dp[d];
    float4 hv = *(const float4*)&hinit[gidx * D_STATE + 4 * j];
    float h0 = hv.x, h1 = hv.y, h2 = hv.z, h3 = hv.w;
    long tok0 = (long)b * SEQLEN + c * CHUNK;
    const ushort* dp = deltaT + (long)d * NTOK + tok0;
    const ushort* xp = xbT + (long)d * NTOK + tok0;
    const ushort* zp = zT + (long)d * NTOK + tok0;
    ushort* yp = yT + (long)d * NTOK + tok0;
    const float* Bp = xpj + tok0 * XPJ_N + DT_RANK + 4 * j;
    #pragma unroll
    for (int t8 = 0; t8 < CHUNK / 8; ++t8) {
        ushort8v dl8 = *(const ushort8v*)dp; dp += 8;
        ushort8v x8  = *(const ushort8v*)xp; xp += 8;
        ushort8v z8 = {0,0,0,0,0,0,0,0};
        if (j == 0) z8 = *(const ushort8v*)zp;
        zp += 8;
        ushort8v y8;
        #pragma unroll
        for (int k = 0; k < 8; ++k) {
            float dl = bf2f(dl8[k]);
            float x  = bf2f(x8[k]);
            float4 Bv = *(const float4*)Bp;
            float4 Cv = *(const float4*)(Bp + D_STATE);
            Bp += XPJ_N;
            float ux = dl * x;
            h0 = exp2f(dl * a0) * h0 + ux * Bv.x;
            h1 = exp2f(dl * a1) * h1 + ux * Bv.y;
            h2 = exp2f(dl * a2) * h2 + ux * Bv.z;
            h3 = exp2f(dl * a3) * h3 + ux * Bv.w;
            float p = h0 * Cv.x + h1 * Cv.y + h2 * Cv.z + h3 * Cv.w;
            p += __shfl_xor(p, 1);
            p += __shfl_xor(p, 2);
            if (j == 0) {
                float z = bf2f(z8[k]);
                y8[k] = f2bf_bits((p + x * dpar) * (z * sigmoidf_(z)));
            }
        }
        if (j == 0) *(ushort8v*)yp = y8;
        yp += 8;
    }
}

extern "C" void kernel_launch(void* const* d_in, const int* in_sizes, int n_in,
                              void* d_out, int out_size, void* d_ws, size_t ws_size,
                              hipStream_t stream) {
    const float* x         = (const float*)d_in[0];
    const float* ln_gamma  = (const float*)d_in[1];
    const float* ln_beta   = (const float*)d_in[2];
    const float* in_proj_w = (const float*)d_in[3];
    const float* conv_w    = (const float*)d_in[4];
    const float* conv_b    = (const float*)d_in[5];
    const float* x_proj_w  = (const float*)d_in[6];
    const float* dt_proj_w = (const float*)d_in[7];
    const float* dt_proj_b = (const float*)d_in[8];
    const float* A_log     = (const float*)d_in[9];
    const float* D_param   = (const float*)d_in[10];
    const float* out_proj_w= (const float*)d_in[11];
    float* out = (float*)d_out;

    // Clean disjoint arena (d_ws is ~268 MB; total used ≈ 154 MB).
    float* p = (float*)d_ws;
    ushort* hb     = (ushort*)p; p += 1048576;   // [2048][1024] bf16
    ushort* W2T    = (ushort*)p; p += 2097152;   // [4096][1024] bf16
    ushort* W7T    = (ushort*)p; p += 1048576;   // [1024][2048] bf16
    ushort* XPT    = (ushort*)p; p += 163840;    // [160][2048] bf16
    ushort* DTT    = (ushort*)p; p += 131072;    // [2048][128] bf16
    ushort* xzb    = (ushort*)p; p += 2097152;   // [2048 tok][2048 d] bf16
    ushort* zT     = (ushort*)p; p += 2097152;   // [2048 d][2048 tok] bf16
    ushort* xbb    = (ushort*)p; p += 2097152;   // [tok][d] bf16
    ushort* xbT    = (ushort*)p; p += 2097152;   // [d][tok] bf16
    float*  xpj    = p;          p += 327680;    // [tok][160] f32
    ushort* dtr    = (ushort*)p; p += 131072;    // [tok][128] bf16
    ushort* deltaT = (ushort*)p; p += 2097152;   // [d][tok] bf16
    float*  Ppart  = p;          p += 2621440;   // gemm4 partials [8][2048][160]
    float*  Pbuf   = p;          p += 2097152;   // scan P
    float*  Hbuf   = p;          p += 2097152;   // scan H
    float*  hinit  = p;          p += 2097152;
    ushort* yT     = (ushort*)p; p += 2097152;   // [d][tok] bf16
    ushort* yb     = (ushort*)p; p += 2097152;   // [tok][d] bf16
    float*  PpartO = p;          p += 8388608;   // out_proj partials [4][2048][1024]

    // 0. weight transposes
    transpose_bf16_kernel<<<dim3(NPROJ / 64, D_MODEL / 64), 256, 0, stream>>>(
        in_proj_w, W2T, D_MODEL, NPROJ);
    transpose_bf16_kernel<<<dim3(D_MODEL / 64, D_INNER / 64), 256, 0, stream>>>(
        out_proj_w, W7T, D_INNER, D_MODEL);
    transpose_bf16_kernel<<<dim3((XPJ_N + 63) / 64, D_INNER / 64), 256, 0, stream>>>(
        x_proj_w, XPT, D_INNER, XPJ_N);
    transpose_bf16_kernel<<<dim3(D_INNER / 64, DT_RANK / 64), 256, 0, stream>>>(
        dt_proj_w, DTT, DT_RANK, D_INNER);

    // 1. LayerNorm → bf16
    ln_kernel<<<NTOK, 256, 0, stream>>>(x, ln_gamma, ln_beta, hb);

    // 2. xz = h @ in_proj_w (MFMA): xb-half → xzb [tok][d]; z-half → zT [d][tok]
    gemm_mfma_kernel<0, 2><<<dim3(NPROJ / 128, NTOK / 128), 256, 0, stream>>>(
        hb, W2T, nullptr, nullptr, xzb, zT, NTOK, NPROJ, D_MODEL, D_MODEL, D_MODEL);

    // 3. conv4 + bias + SiLU → xbb [tok][d]
    conv_silu_kernel<<<(NTOK * D_INNER) / 256, 256, 0, stream>>>(
        xzb, conv_w, conv_b, xbb);

    // 3b. xbT = xbb^T [d][tok]
    transpose_bb_kernel<<<dim3(D_INNER / 64, NTOK / 64), 256, 0, stream>>>(
        xbb, xbT, NTOK, D_INNER);

    // 4. xpj partials (split-K MFMA) then reduce → xpj f32 + dtr bf16
    gemm4_mfma_kernel<<<dim3(SPLITK, NTOK / 64), 256, 0, stream>>>(
        xbb, XPT, Ppart, NTOK, D_INNER);
    reduce_xpj_kernel<<<(NTOK * XPJ_N) / 256, 256, 0, stream>>>(Ppart, xpj, dtr);

    // 5. deltaT = softplus(dt_r @ dt_proj_w + b)^T (MFMA 128x64, transposed bf16 store)
    gemm_mfma64T_kernel<<<dim3(D_INNER / 64, NTOK / 128), 256, 0, stream>>>(
        dtr, DTT, dt_proj_b, deltaT, NTOK, D_INNER, DT_RANK);

    // 6. chunked selective scan (time-contiguous, ushort8 loads)
    scan_partial_kernel<<<(BATCH * NCHUNK * D_INNER) / 64, 256, 0, stream>>>(
        deltaT, xbT, xpj, A_log, Pbuf, Hbuf);
    scan_chunkscan_kernel<<<(BATCH * D_INNER * D_STATE) / 256, 256, 0, stream>>>(
        Pbuf, Hbuf, hinit);
    scan_final_kernel<<<(BATCH * NCHUNK * D_INNER) / 64, 256, 0, stream>>>(
        deltaT, xbT, xpj, zT, A_log, D_param, hinit, yT);

    // 6b. y = yT^T [tok][d]
    transpose_bb_kernel<<<dim3(NTOK / 64, D_INNER / 64), 256, 0, stream>>>(
        yT, yb, D_INNER, NTOK);

    // 7. out_proj split-K=4: partials then fused reduce+residual
    gemm_mfma_kernel<0, 0><<<dim3(D_MODEL / 128, NTOK / 128, OP_SPLITK), 256, 0, stream>>>(
        yb, W7T, nullptr, PpartO, nullptr, nullptr, NTOK, D_MODEL, D_INNER / OP_SPLITK,
        D_INNER, D_INNER);
    reduce_out_kernel<<<(NTOK * D_MODEL / 4) / 256, 256, 0, stream>>>(PpartO, x, out);
}

// Round 11
// 203.366 us; speedup vs baseline: 1.0737x; 1.0737x over previous
//
#include <hip/hip_runtime.h>
#include <hip/hip_bf16.h>

#define D_MODEL 1024
#define D_INNER 2048
#define NPROJ   4096   /* 2*D_INNER */
#define D_STATE 16
#define DT_RANK 128
#define XPJ_N   160    /* DT_RANK + 2*D_STATE */
#define SEQLEN  1024
#define BATCH   2
#define NTOK    2048   /* BATCH*SEQLEN */
#define CHUNK   32
#define NCHUNK  (SEQLEN / CHUNK)   /* 32 */
#define LOG2_NCHUNK 5
#define SPLITK  8      /* gemm4 split */
#define OP_SPLITK 4    /* out_proj split */

typedef short short8 __attribute__((ext_vector_type(8)));
typedef float f32x4 __attribute__((ext_vector_type(4)));

__device__ __forceinline__ float sigmoidf_(float x) { return 1.f / (1.f + __expf(-x)); }
__device__ __forceinline__ ushort f2bf_bits(float f) {
    __hip_bfloat16 h = __float2bfloat16(f);
    return *(ushort*)&h;
}
__device__ __forceinline__ float bf2f(ushort u) {
    union { unsigned int i; float f; } v;
    v.i = ((unsigned int)u) << 16;
    return v.f;
}
// In-quad butterfly adds via DPP quad_perm (no LDS pipe, unlike __shfl_xor).
__device__ __forceinline__ float quad_xor1_add(float p) {
    int q = __builtin_amdgcn_mov_dpp(__float_as_int(p), 0xB1, 0xF, 0xF, true); // [1,0,3,2]
    return p + __int_as_float(q);
}
__device__ __forceinline__ float quad_xor2_add(float p) {
    int q = __builtin_amdgcn_mov_dpp(__float_as_int(p), 0x4E, 0xF, 0xF, true); // [2,3,0,1]
    return p + __int_as_float(q);
}

// ---------------- LayerNorm → bf16 output ----------------
__global__ __launch_bounds__(256) void ln_kernel(const float* __restrict__ x,
                                                 const float* __restrict__ g,
                                                 const float* __restrict__ be,
                                                 ushort* __restrict__ hb)
{
    int row = blockIdx.x;
    const float4* xr = (const float4*)(x + (long)row * D_MODEL);
    float4 v = xr[threadIdx.x];
    float s1 = v.x + v.y + v.z + v.w;
    float s2 = v.x*v.x + v.y*v.y + v.z*v.z + v.w*v.w;
    for (int off = 32; off >= 1; off >>= 1) {
        s1 += __shfl_down(s1, off);
        s2 += __shfl_down(s2, off);
    }
    __shared__ float red[8];
    int wid = threadIdx.x >> 6;
    if ((threadIdx.x & 63) == 0) { red[wid] = s1; red[4 + wid] = s2; }
    __syncthreads();
    float mu  = (red[0] + red[1] + red[2] + red[3]) * (1.f / D_MODEL);
    float ex2 = (red[4] + red[5] + red[6] + red[7]) * (1.f / D_MODEL);
    float inv = rsqrtf(ex2 - mu * mu + 1e-5f);
    float4 g4 = ((const float4*)g)[threadIdx.x];
    float4 b4 = ((const float4*)be)[threadIdx.x];
    ushort4 o;
    o.x = f2bf_bits((v.x - mu) * inv * g4.x + b4.x);
    o.y = f2bf_bits((v.y - mu) * inv * g4.y + b4.y);
    o.z = f2bf_bits((v.z - mu) * inv * g4.z + b4.z);
    o.w = f2bf_bits((v.w - mu) * inv * g4.w + b4.w);
    *(ushort4*)(hb + (long)row * D_MODEL + threadIdx.x * 4) = o;
}

// ---------------- f32 [R][C] → bf16 [C][R] transpose (guarded) ----------------
__global__ __launch_bounds__(256) void transpose_bf16_kernel(const float* __restrict__ in,
                                                             ushort* __restrict__ out,
                                                             int R, int C)
{
    __shared__ float tile[64][65];
    int c0 = blockIdx.x * 64, r0 = blockIdx.y * 64;
    #pragma unroll
    for (int i = 0; i < 16; ++i) {
        int idx = threadIdx.x + i * 256;
        int r = idx >> 6, c = idx & 63;
        tile[r][c] = (r0 + r < R && c0 + c < C) ? in[(long)(r0 + r) * C + (c0 + c)] : 0.f;
    }
    __syncthreads();
    #pragma unroll
    for (int i = 0; i < 16; ++i) {
        int idx = threadIdx.x + i * 256;
        int cc = idx >> 6, rr = idx & 63;
        if (c0 + cc < C && r0 + rr < R)
            out[(long)(c0 + cc) * R + (r0 + rr)] = f2bf_bits(tile[rr][cc]);
    }
}

// ---------------- bf16 MFMA GEMM 128x128: C = A[M,K(lda)] * Bt[N,K(ldb)]^T -----------
// blockIdx.z advances A,Bt by z*K and Cf by z*M*N (split-K).
// EPI 0: v=acc ; EPI 1: v=softplus(acc+bias[n])
// OBF 0: store f32 to Cf ; OBF 1: store bf16 to Cb
template <int EPI, int OBF>
__global__ __launch_bounds__(256) void gemm_mfma_kernel(const ushort* __restrict__ A,
                                                        const ushort* __restrict__ Bt,
                                                        const float* __restrict__ bias,
                                                        float* __restrict__ Cf,
                                                        ushort* __restrict__ Cb,
                                                        int M, int N, int K, int lda, int ldb)
{
    long zoff = (long)blockIdx.z;
    A  += zoff * K;
    Bt += zoff * K;
    if (OBF == 0) Cf += zoff * (long)M * N;
    __shared__ __align__(16) ushort Al[128 * 32];
    __shared__ __align__(16) ushort Bl[128 * 32];
    int tid = threadIdx.x;
    int lane = tid & 63;
    int w = tid >> 6, wr = w >> 1, wc = w & 1;
    int m0 = blockIdx.y * 128, n0 = blockIdx.x * 128;
    f32x4 acc[4][4];
    #pragma unroll
    for (int m = 0; m < 4; ++m)
        #pragma unroll
        for (int n = 0; n < 4; ++n) acc[m][n] = (f32x4){0.f, 0.f, 0.f, 0.f};
    int l15 = lane & 15, kq = lane >> 4;

    for (int k0 = 0; k0 < K; k0 += 32) {
        #pragma unroll
        for (int i = 0; i < 2; ++i) {
            int s = i * 256 + tid;
            int row = s >> 2, kg = s & 3;
            int kgl = kg ^ ((row >> 1) & 3);
            __builtin_amdgcn_global_load_lds(
                (const __attribute__((address_space(1))) void*)(A + (long)(m0 + row) * lda + k0 + kgl * 8),
                (__attribute__((address_space(3))) void*)(Al + s * 8), 16, 0, 0);
            __builtin_amdgcn_global_load_lds(
                (const __attribute__((address_space(1))) void*)(Bt + (long)(n0 + row) * ldb + k0 + kgl * 8),
                (__attribute__((address_space(3))) void*)(Bl + s * 8), 16, 0, 0);
        }
        __syncthreads();
        short8 af[4], bf[4];
        #pragma unroll
        for (int m = 0; m < 4; ++m) {
            int row = wr * 64 + m * 16 + l15;
            af[m] = *(const short8*)&Al[row * 32 + (kq ^ ((row >> 1) & 3)) * 8];
        }
        #pragma unroll
        for (int n = 0; n < 4; ++n) {
            int row = wc * 64 + n * 16 + l15;
            bf[n] = *(const short8*)&Bl[row * 32 + (kq ^ ((row >> 1) & 3)) * 8];
        }
        #pragma unroll
        for (int m = 0; m < 4; ++m)
            #pragma unroll
            for (int n = 0; n < 4; ++n)
                acc[m][n] = __builtin_amdgcn_mfma_f32_16x16x32_bf16(af[m], bf[n], acc[m][n], 0, 0, 0);
        __syncthreads();
    }
    #pragma unroll
    for (int m = 0; m < 4; ++m) {
        #pragma unroll
        for (int n = 0; n < 4; ++n) {
            #pragma unroll
            for (int r = 0; r < 4; ++r) {
                int row = m0 + wr * 64 + m * 16 + kq * 4 + r;
                int col = n0 + wc * 64 + n * 16 + l15;
                float v = acc[m][n][r];
                if (EPI == 1) {
                    v += bias[col];
                    v = (v > 20.f) ? v : log1pf(__expf(v));
                }
                if (OBF) Cb[(long)row * N + col] = f2bf_bits(v);
                else     Cf[(long)row * N + col] = v;
            }
        }
    }
}

// ---------------- bf16 MFMA GEMM 128x64 ----------------
template <int EPI, int OBF>
__global__ __launch_bounds__(256) void gemm_mfma64_kernel(const ushort* __restrict__ A,
                                                          const ushort* __restrict__ Bt,
                                                          const float* __restrict__ bias,
                                                          float* __restrict__ Cf,
                                                          ushort* __restrict__ Cb,
                                                          int M, int N, int K)
{
    __shared__ __align__(16) ushort Al[128 * 32];
    __shared__ __align__(16) ushort Bl[64 * 32];
    int tid = threadIdx.x;
    int lane = tid & 63;
    int w = tid >> 6, wr = w >> 1, wc = w & 1;
    int m0 = blockIdx.y * 128, n0 = blockIdx.x * 64;
    f32x4 acc[4][2];
    #pragma unroll
    for (int m = 0; m < 4; ++m)
        #pragma unroll
        for (int n = 0; n < 2; ++n) acc[m][n] = (f32x4){0.f, 0.f, 0.f, 0.f};
    int l15 = lane & 15, kq = lane >> 4;

    for (int k0 = 0; k0 < K; k0 += 32) {
        #pragma unroll
        for (int i = 0; i < 2; ++i) {
            int s = i * 256 + tid;
            int row = s >> 2, kg = s & 3;
            int kgl = kg ^ ((row >> 1) & 3);
            __builtin_amdgcn_global_load_lds(
                (const __attribute__((address_space(1))) void*)(A + (long)(m0 + row) * K + k0 + kgl * 8),
                (__attribute__((address_space(3))) void*)(Al + s * 8), 16, 0, 0);
        }
        {
            int s = tid;
            int row = s >> 2, kg = s & 3;
            int kgl = kg ^ ((row >> 1) & 3);
            __builtin_amdgcn_global_load_lds(
                (const __attribute__((address_space(1))) void*)(Bt + (long)(n0 + row) * K + k0 + kgl * 8),
                (__attribute__((address_space(3))) void*)(Bl + s * 8), 16, 0, 0);
        }
        __syncthreads();
        short8 af[4], bf[2];
        #pragma unroll
        for (int m = 0; m < 4; ++m) {
            int row = wr * 64 + m * 16 + l15;
            af[m] = *(const short8*)&Al[row * 32 + (kq ^ ((row >> 1) & 3)) * 8];
        }
        #pragma unroll
        for (int n = 0; n < 2; ++n) {
            int row = wc * 32 + n * 16 + l15;
            bf[n] = *(const short8*)&Bl[row * 32 + (kq ^ ((row >> 1) & 3)) * 8];
        }
        #pragma unroll
        for (int m = 0; m < 4; ++m)
            #pragma unroll
            for (int n = 0; n < 2; ++n)
                acc[m][n] = __builtin_amdgcn_mfma_f32_16x16x32_bf16(af[m], bf[n], acc[m][n], 0, 0, 0);
        __syncthreads();
    }
    #pragma unroll
    for (int m = 0; m < 4; ++m) {
        #pragma unroll
        for (int n = 0; n < 2; ++n) {
            #pragma unroll
            for (int r = 0; r < 4; ++r) {
                int row = m0 + wr * 64 + m * 16 + kq * 4 + r;
                int col = n0 + wc * 32 + n * 16 + l15;
                float v = acc[m][n][r];
                if (EPI == 1) {
                    v += bias[col];
                    v = (v > 20.f) ? v : log1pf(__expf(v));
                }
                if (OBF) Cb[(long)row * N + col] = f2bf_bits(v);
                else     Cf[(long)row * N + col] = v;
            }
        }
    }
}

// -------- out_proj split-K reduce: out = sum_k Ppart[k] + resid --------
__global__ __launch_bounds__(256) void reduce_out_kernel(const float* __restrict__ Ppart,
                                                         const float* __restrict__ resid,
                                                         float* __restrict__ out)
{
    long i = (long)blockIdx.x * 256 + threadIdx.x;
    const long STRIDE = (long)NTOK * D_MODEL / 4;
    float4 s = ((const float4*)Ppart)[i];
    #pragma unroll
    for (int k = 1; k < OP_SPLITK; ++k) {
        float4 p = ((const float4*)Ppart)[k * STRIDE + i];
        s.x += p.x; s.y += p.y; s.z += p.z; s.w += p.w;
    }
    float4 r = ((const float4*)resid)[i];
    s.x += r.x; s.y += r.y; s.z += r.z; s.w += r.w;
    ((float4*)out)[i] = s;
}

// -------- split-K bf16 MFMA GEMM for xpj --------
__global__ __launch_bounds__(256) void gemm4_mfma_kernel(const ushort* __restrict__ A,
                                                         const ushort* __restrict__ Bt,
                                                         float* __restrict__ Ppart,
                                                         int M, int K)
{
    __shared__ __align__(16) ushort Al[64 * 32];
    __shared__ __align__(16) ushort Bl[160 * 32];
    int tid = threadIdx.x;
    int lane = tid & 63;
    int w = tid >> 6, wr = w >> 1, wc = w & 1;
    int sk = blockIdx.x;
    int m0 = blockIdx.y * 64;
    int kbase = sk * (K / SPLITK);
    f32x4 acc[2][5];
    #pragma unroll
    for (int m = 0; m < 2; ++m)
        #pragma unroll
        for (int n = 0; n < 5; ++n) acc[m][n] = (f32x4){0.f, 0.f, 0.f, 0.f};
    int l15 = lane & 15, kq = lane >> 4;

    for (int ks = 0; ks < K / SPLITK; ks += 32) {
        int k0 = kbase + ks;
        {
            int s = tid;
            int row = s >> 2, kg = s & 3;
            int kgl = kg ^ ((row >> 1) & 3);
            __builtin_amdgcn_global_load_lds(
                (const __attribute__((address_space(1))) void*)(A + (long)(m0 + row) * K + k0 + kgl * 8),
                (__attribute__((address_space(3))) void*)(Al + s * 8), 16, 0, 0);
        }
        #pragma unroll
        for (int i = 0; i < 3; ++i) {
            int s = i * 256 + tid;
            if (s < 640) {
                int row = s >> 2, kg = s & 3;
                int kgl = kg ^ ((row >> 1) & 3);
                __builtin_amdgcn_global_load_lds(
                    (const __attribute__((address_space(1))) void*)(Bt + (long)row * K + k0 + kgl * 8),
                    (__attribute__((address_space(3))) void*)(Bl + s * 8), 16, 0, 0);
            }
        }
        __syncthreads();
        short8 af[2], bf[5];
        #pragma unroll
        for (int m = 0; m < 2; ++m) {
            int row = wr * 32 + m * 16 + l15;
            af[m] = *(const short8*)&Al[row * 32 + (kq ^ ((row >> 1) & 3)) * 8];
        }
        #pragma unroll
        for (int n = 0; n < 5; ++n) {
            int row = wc * 80 + n * 16 + l15;
            bf[n] = *(const short8*)&Bl[row * 32 + (kq ^ ((row >> 1) & 3)) * 8];
        }
        #pragma unroll
        for (int m = 0; m < 2; ++m)
            #pragma unroll
            for (int n = 0; n < 5; ++n)
                acc[m][n] = __builtin_amdgcn_mfma_f32_16x16x32_bf16(af[m], bf[n], acc[m][n], 0, 0, 0);
        __syncthreads();
    }
    float* P = Ppart + (long)sk * M * XPJ_N;
    #pragma unroll
    for (int m = 0; m < 2; ++m) {
        #pragma unroll
        for (int n = 0; n < 5; ++n) {
            #pragma unroll
            for (int r = 0; r < 4; ++r) {
                int row = m0 + wr * 32 + m * 16 + kq * 4 + r;
                int col = wc * 80 + n * 16 + l15;
                P[(long)row * XPJ_N + col] = acc[m][n][r];
            }
        }
    }
}

// -------- reduce split-K partials → xpj f32 + dt_r bf16 --------
__global__ __launch_bounds__(256) void reduce_xpj_kernel(const float* __restrict__ Ppart,
                                                         float* __restrict__ xpj,
                                                         ushort* __restrict__ dtr)
{
    long i = (long)blockIdx.x * 256 + threadIdx.x;
    float s = 0.f;
    #pragma unroll
    for (int k = 0; k < SPLITK; ++k) s += Ppart[k * (long)NTOK * XPJ_N + i];
    xpj[i] = s;
    int col = (int)(i % XPJ_N);
    long row = i / XPJ_N;
    if (col < DT_RANK) dtr[row * DT_RANK + col] = f2bf_bits(s);
}

// ---------------- depthwise causal conv (width 4) + bias + SiLU; bf16 in/out ----------
__global__ __launch_bounds__(256) void conv_silu_kernel(const ushort* __restrict__ xzb,
                                                        const float* __restrict__ cw,
                                                        const float* __restrict__ cb,
                                                        ushort* __restrict__ xbb)
{
    long i = (long)blockIdx.x * 256 + threadIdx.x;  // over NTOK*D_INNER
    int d = (int)(i & (D_INNER - 1));
    long tok = i >> 11;
    int l = (int)(tok & (SEQLEN - 1));
    float w0 = cw[d * 4 + 0], w1 = cw[d * 4 + 1], w2 = cw[d * 4 + 2], w3 = cw[d * 4 + 3];
    float acc = cb[d];
    acc += bf2f(xzb[tok * NPROJ + d]) * w3;
    if (l >= 1) acc += bf2f(xzb[(tok - 1) * NPROJ + d]) * w2;
    if (l >= 2) acc += bf2f(xzb[(tok - 2) * NPROJ + d]) * w1;
    if (l >= 3) acc += bf2f(xzb[(tok - 3) * NPROJ + d]) * w0;
    float v = acc * sigmoidf_(acc);
    xbb[i] = f2bf_bits(v);
}

// ======================= chunked selective scan (4 lanes/channel, CHUNK=32) ==========
// delta, xb bf16; B,C f32; z bf16.
__global__ __launch_bounds__(256) void scan_partial_kernel(const ushort* __restrict__ deltab,
                                                           const ushort* __restrict__ xbb,
                                                           const float* __restrict__ xpj,
                                                           const float* __restrict__ A_log,
                                                           float* __restrict__ Pout,
                                                           float* __restrict__ Hout)
{
    int tid = threadIdx.x;
    int j = tid & 3, grp = tid >> 2;
    long gidx = (long)blockIdx.x * 64 + grp;      // over BATCH*NCHUNK*D_INNER
    int d = (int)(gidx & (D_INNER - 1));
    int c = (int)((gidx >> 11) & (NCHUNK - 1));
    int b = (int)(gidx >> (11 + LOG2_NCHUNK));
    float4 al = *(const float4*)&A_log[d * D_STATE + 4 * j];
    float a0 = -__expf(al.x), a1 = -__expf(al.y), a2 = -__expf(al.z), a3 = -__expf(al.w);
    float h0 = 0.f, h1 = 0.f, h2 = 0.f, h3 = 0.f, cum = 0.f;
    long tok0 = (long)b * SEQLEN + c * CHUNK;
    const ushort* dp = deltab + tok0 * D_INNER + d;
    const ushort* xp = xbb + tok0 * D_INNER + d;
    const float* Bp = xpj + tok0 * XPJ_N + DT_RANK + 4 * j;
    for (int t = 0; t < CHUNK; ++t) {
        float dl = bf2f(*dp);
        float x  = bf2f(*xp);
        float4 Bv = *(const float4*)Bp;
        dp += D_INNER; xp += D_INNER; Bp += XPJ_N;
        cum += dl;
        float ux = dl * x;
        h0 = __expf(dl * a0) * h0 + ux * Bv.x;
        h1 = __expf(dl * a1) * h1 + ux * Bv.y;
        h2 = __expf(dl * a2) * h2 + ux * Bv.z;
        h3 = __expf(dl * a3) * h3 + ux * Bv.w;
    }
    long o = gidx * D_STATE + 4 * j;
    *(float4*)&Pout[o] = (float4){__expf(a0 * cum), __expf(a1 * cum), __expf(a2 * cum), __expf(a3 * cum)};
    *(float4*)&Hout[o] = (float4){h0, h1, h2, h3};
}

__global__ __launch_bounds__(256) void scan_chunkscan_kernel(const float* __restrict__ P,
                                                             const float* __restrict__ H,
                                                             float* __restrict__ hinit)
{
    long i = (long)blockIdx.x * 256 + threadIdx.x;  // over BATCH*D_INNER*D_STATE
    int n = (int)(i & (D_STATE - 1));
    int d = (int)((i >> 4) & (D_INNER - 1));
    int b = (int)(i >> 15);
    float h = 0.f;
    for (int c = 0; c < NCHUNK; ++c) {
        long o = ((((long)b * NCHUNK + c) * D_INNER + d) * D_STATE) + n;
        hinit[o] = h;
        h = P[o] * h + H[o];
    }
}

__global__ __launch_bounds__(256) void scan_final_kernel(const ushort* __restrict__ deltab,
                                                         const ushort* __restrict__ xbb,
                                                         const float* __restrict__ xpj,
                                                         const ushort* __restrict__ xzb,
                                                         const float* __restrict__ A_log,
                                                         const float* __restrict__ Dp,
                                                         const float* __restrict__ hinit,
                                                         ushort* __restrict__ yb)
{
    int tid = threadIdx.x;
    int j = tid & 3, grp = tid >> 2;
    long gidx = (long)blockIdx.x * 64 + grp;
    int d = (int)(gidx & (D_INNER - 1));
    int c = (int)((gidx >> 11) & (NCHUNK - 1));
    int b = (int)(gidx >> (11 + LOG2_NCHUNK));
    float4 al = *(const float4*)&A_log[d * D_STATE + 4 * j];
    float a0 = -__expf(al.x), a1 = -__expf(al.y), a2 = -__expf(al.z), a3 = -__expf(al.w);
    float dpar = Dp[d];
    float4 hv = *(const float4*)&hinit[gidx * D_STATE + 4 * j];
    float h0 = hv.x, h1 = hv.y, h2 = hv.z, h3 = hv.w;
    long tok0 = (long)b * SEQLEN + c * CHUNK;
    const ushort* dp = deltab + tok0 * D_INNER + d;
    const ushort* xp = xbb + tok0 * D_INNER + d;
    const float* Bp = xpj + tok0 * XPJ_N + DT_RANK + 4 * j;
    const float* Cp = Bp + D_STATE;
    const ushort* zp = xzb + tok0 * NPROJ + D_INNER + d;
    ushort* yp = yb + tok0 * D_INNER + d;
    for (int t = 0; t < CHUNK; ++t) {
        float dl = bf2f(*dp);
        float x  = bf2f(*xp);
        float4 Bv = *(const float4*)Bp;
        float4 Cv = *(const float4*)Cp;
        dp += D_INNER; xp += D_INNER; Bp += XPJ_N; Cp += XPJ_N;
        float ux = dl * x;
        h0 = __expf(dl * a0) * h0 + ux * Bv.x;
        h1 = __expf(dl * a1) * h1 + ux * Bv.y;
        h2 = __expf(dl * a2) * h2 + ux * Bv.z;
        h3 = __expf(dl * a3) * h3 + ux * Bv.w;
        float p = h0 * Cv.x + h1 * Cv.y + h2 * Cv.z + h3 * Cv.w;
        p = quad_xor1_add(p);
        p = quad_xor2_add(p);
        if (j == 0) {
            float z = bf2f(*zp);
            float y = p + x * dpar;
            *yp = f2bf_bits(y * (z * sigmoidf_(z)));
        }
        zp += NPROJ; yp += D_INNER;
    }
}

extern "C" void kernel_launch(void* const* d_in, const int* in_sizes, int n_in,
                              void* d_out, int out_size, void* d_ws, size_t ws_size,
                              hipStream_t stream) {
    const float* x         = (const float*)d_in[0];
    const float* ln_gamma  = (const float*)d_in[1];
    const float* ln_beta   = (const float*)d_in[2];
    const float* in_proj_w = (const float*)d_in[3];
    const float* conv_w    = (const float*)d_in[4];
    const float* conv_b    = (const float*)d_in[5];
    const float* x_proj_w  = (const float*)d_in[6];
    const float* dt_proj_w = (const float*)d_in[7];
    const float* dt_proj_b = (const float*)d_in[8];
    const float* A_log     = (const float*)d_in[9];
    const float* D_param   = (const float*)d_in[10];
    const float* out_proj_w= (const float*)d_in[11];
    float* out = (float*)d_out;

    // Clean disjoint arena (d_ws ≈ 268 MB; used ≈ 150 MB).
    float* p = (float*)d_ws;
    ushort* hb      = (ushort*)p; p += 1048576;   // [2048][1024] bf16
    ushort* W2T     = (ushort*)p; p += 2097152;   // [4096][1024] bf16
    ushort* W7T     = (ushort*)p; p += 1048576;   // [1024][2048] bf16
    ushort* XPT     = (ushort*)p; p += 163840;    // [160][2048] bf16
    ushort* DTT     = (ushort*)p; p += 131072;    // [2048][128] bf16
    ushort* xz_bf16 = (ushort*)p; p += 4194304;   // [2048 tok][4096] bf16
    ushort* xb_bf16 = (ushort*)p; p += 2097152;   // [tok][2048] bf16
    float*  xpj     = p;          p += 327680;    // [tok][160] f32
    ushort* dtr     = (ushort*)p; p += 131072;    // [tok][128] bf16
    ushort* delta_bf16 = (ushort*)p; p += 2097152;// [tok][2048] bf16
    float*  Ppart   = p;          p += 2621440;   // gemm4 partials [8][2048][160]
    float*  Pbuf    = p;          p += 2097152;   // scan P
    float*  Hbuf    = p;          p += 2097152;   // scan H
    float*  hinit   = p;          p += 2097152;
    ushort* y_bf16  = (ushort*)p; p += 2097152;   // [tok][2048] bf16
    float*  PpartO  = p;          p += 8388608;   // out_proj partials [4][2048][1024]

    // 0. weight transposes
    transpose_bf16_kernel<<<dim3(NPROJ / 64, D_MODEL / 64), 256, 0, stream>>>(
        in_proj_w, W2T, D_MODEL, NPROJ);
    transpose_bf16_kernel<<<dim3(D_MODEL / 64, D_INNER / 64), 256, 0, stream>>>(
        out_proj_w, W7T, D_INNER, D_MODEL);
    transpose_bf16_kernel<<<dim3((XPJ_N + 63) / 64, D_INNER / 64), 256, 0, stream>>>(
        x_proj_w, XPT, D_INNER, XPJ_N);
    transpose_bf16_kernel<<<dim3(D_INNER / 64, DT_RANK / 64), 256, 0, stream>>>(
        dt_proj_w, DTT, DT_RANK, D_INNER);

    // 1. LayerNorm → bf16
    ln_kernel<<<NTOK, 256, 0, stream>>>(x, ln_gamma, ln_beta, hb);

    // 2. xz = h @ in_proj_w (MFMA, bf16 out) [2048,1024]x[1024,4096]
    gemm_mfma_kernel<0, 1><<<dim3(NPROJ / 128, NTOK / 128), 256, 0, stream>>>(
        hb, W2T, nullptr, nullptr, xz_bf16, NTOK, NPROJ, D_MODEL, D_MODEL, D_MODEL);

    // 3. conv4 + bias + SiLU (bf16 in/out)
    conv_silu_kernel<<<(NTOK * D_INNER) / 256, 256, 0, stream>>>(
        xz_bf16, conv_w, conv_b, xb_bf16);

    // 4. xpj partials (split-K MFMA) then reduce → xpj f32 + dtr bf16
    gemm4_mfma_kernel<<<dim3(SPLITK, NTOK / 64), 256, 0, stream>>>(
        xb_bf16, XPT, Ppart, NTOK, D_INNER);
    reduce_xpj_kernel<<<(NTOK * XPJ_N) / 256, 256, 0, stream>>>(Ppart, xpj, dtr);

    // 5. delta = softplus(dt_r @ dt_proj_w + b) (MFMA 128x64, bf16 out)
    gemm_mfma64_kernel<1, 1><<<dim3(D_INNER / 64, NTOK / 128), 256, 0, stream>>>(
        dtr, DTT, dt_proj_b, nullptr, delta_bf16, NTOK, D_INNER, DT_RANK);

    // 6. chunked selective scan (4 lanes/channel, CHUNK=32, DPP reduces)
    scan_partial_kernel<<<(BATCH * NCHUNK * D_INNER) / 64, 256, 0, stream>>>(
        delta_bf16, xb_bf16, xpj, A_log, Pbuf, Hbuf);
    scan_chunkscan_kernel<<<(BATCH * D_INNER * D_STATE) / 256, 256, 0, stream>>>(
        Pbuf, Hbuf, hinit);
    scan_final_kernel<<<(BATCH * NCHUNK * D_INNER) / 64, 256, 0, stream>>>(
        delta_bf16, xb_bf16, xpj, xz_bf16, A_log, D_param, hinit, y_bf16);

    // 7. out_proj split-K=4: partials then fused reduce+residual
    gemm_mfma_kernel<0, 0><<<dim3(D_MODEL / 128, NTOK / 128, OP_SPLITK), 256, 0, stream>>>(
        y_bf16, W7T, nullptr, PpartO, nullptr, NTOK, D_MODEL, D_INNER / OP_SPLITK,
        D_INNER, D_INNER);
    reduce_out_kernel<<<(NTOK * D_MODEL / 4) / 256, 256, 0, stream>>>(PpartO, x, out);
}